// Round 8
// baseline (138.544 us; speedup 1.0000x reference)
//
#include <hip/hip_runtime.h>
#include <math.h>

#define HIDDEN 256
#define CHUNK 8

typedef float fx4 __attribute__((ext_vector_type(4)));

// Single kernel: block = 4 waves = 1 graph. Per-block binary search over the
// sorted batch array yields [start, end) — no separate seg_starts kernel, no
// inter-kernel dependency bubble. Each wave takes a quarter of the graph's
// chunks; remainder is a masked vector chunk; 4 online-softmax states merged
// via LDS.
__global__ __launch_bounds__(256) void pool_kernel(
    const float* __restrict__ h, const float* __restrict__ node_mult,
    const float* __restrict__ pressure, const float* __restrict__ attn_weight,
    const float* __restrict__ attn_bias, const float* __restrict__ W_pressure,
    const int* __restrict__ batch, float* __restrict__ out, int N, int G) {
  const int q    = threadIdx.x >> 6;   // wave 0..3 = quarter index
  const int lane = threadIdx.x & 63;
  const int g = blockIdx.x;

  __shared__ float s_m[3], s_d[3], s_t[3];
  __shared__ fx4 s_attn[3][64], s_mean[3][64], s_max[3][64];

  // lower_bound(batch, g + (lane&1)): even lanes -> start, odd lanes -> end.
  // Branch-free fixed 20 iterations (2^20 > N).
  {
  }
  const int v = g + (lane & 1);
  int lo = 0, hi = N;
#pragma unroll 1
  for (int it = 0; it < 20; ++it) {
    if (lo < hi) {
      const int mid = (lo + hi) >> 1;
      if (batch[mid] < v) lo = mid + 1; else hi = mid;
    }
  }
  const int start = __shfl(lo, 0, 64);
  const int end   = __shfl(lo, 1, 64);

  const int total = end - start;
  const int nfull = total / CHUNK;          // full chunks
  const int rem   = total - nfull * CHUNK;  // 0..7
  const int nt    = nfull + (rem > 0);      // total chunks incl. masked

  const fx4 w4 = *reinterpret_cast<const fx4*>(attn_weight + 4 * lane);
  const float bias = attn_bias[0];

  fx4 attn  = (fx4)(0.f);
  fx4 meanv = (fx4)(0.f);
  fx4 maxv  = (fx4)(-INFINITY);
  float m = -INFINITY;
  float denom = 0.f;
  float tmult = 0.f;

  // this wave's chunk range [c_lo, c_hi) over all nt chunks
  const int c_lo = (q * nt) / 4;
  const int c_hi = ((q + 1) * nt) / 4;
  const int f_hi = (c_hi < nfull) ? c_hi : nfull;  // full-chunk part

  for (int c = c_lo; c < f_hi; ++c) {
    const int i = start + c * CHUNK;
    fx4 hv[CHUNK];
    float mult[CHUNK];
#pragma unroll
    for (int j = 0; j < CHUNK; ++j) {
      hv[j] = __builtin_nontemporal_load(
          reinterpret_cast<const fx4*>(h + (size_t)(i + j) * HIDDEN + 4 * lane));
      mult[j] = node_mult[i + j];
    }

    float p[CHUNK];
#pragma unroll
    for (int j = 0; j < CHUNK; ++j)
      p[j] = hv[j].x * w4.x + hv[j].y * w4.y + hv[j].z * w4.z + hv[j].w * w4.w;

#pragma unroll
    for (int off = 32; off >= 1; off >>= 1) {
#pragma unroll
      for (int j = 0; j < CHUNK; ++j) p[j] += __shfl_xor(p[j], off, 64);
    }

    float s[CHUNK];
#pragma unroll
    for (int j = 0; j < CHUNK; ++j)
      s[j] = p[j] + bias + __logf(fmaxf(mult[j], 1.f));

    float cmax = s[0];
#pragma unroll
    for (int j = 1; j < CHUNK; ++j) cmax = fmaxf(cmax, s[j]);

    if (cmax > m) {
      const float scale = __expf(m - cmax);  // m=-inf -> 0
      denom *= scale;
      attn *= scale;
      m = cmax;
    }

#pragma unroll
    for (int j = 0; j < CHUNK; ++j) {
      const float e = __expf(s[j] - m);
      denom += e;
      attn += hv[j] * e;
      meanv += hv[j] * mult[j];
      maxv.x = fmaxf(maxv.x, hv[j].x);  maxv.y = fmaxf(maxv.y, hv[j].y);
      maxv.z = fmaxf(maxv.z, hv[j].z);  maxv.w = fmaxf(maxv.w, hv[j].w);
      tmult += mult[j];
    }
  }

  // masked remainder chunk (1..7 nodes), owned by the wave whose range has it
  if (rem > 0 && c_lo <= nfull && nfull < c_hi) {
    const int base = start + nfull * CHUNK;
    fx4 hv[CHUNK];
    float mult[CHUNK];
#pragma unroll
    for (int j = 0; j < CHUNK; ++j) {
      const int idx = base + ((j < rem) ? j : rem - 1);  // clamped, in-bounds
      hv[j] = __builtin_nontemporal_load(
          reinterpret_cast<const fx4*>(h + (size_t)idx * HIDDEN + 4 * lane));
      mult[j] = (j < rem) ? node_mult[base + j] : 0.f;
    }

    float p[CHUNK];
#pragma unroll
    for (int j = 0; j < CHUNK; ++j)
      p[j] = hv[j].x * w4.x + hv[j].y * w4.y + hv[j].z * w4.z + hv[j].w * w4.w;

#pragma unroll
    for (int off = 32; off >= 1; off >>= 1) {
#pragma unroll
      for (int j = 0; j < CHUNK; ++j) p[j] += __shfl_xor(p[j], off, 64);
    }

    float s[CHUNK];
#pragma unroll
    for (int j = 0; j < CHUNK; ++j)
      s[j] = (j < rem) ? (p[j] + bias + __logf(fmaxf(mult[j], 1.f))) : -INFINITY;

    float cmax = s[0];
#pragma unroll
    for (int j = 1; j < CHUNK; ++j) cmax = fmaxf(cmax, s[j]);

    if (cmax > m) {
      const float scale = __expf(m - cmax);
      denom *= scale;
      attn *= scale;
      m = cmax;
    }

#pragma unroll
    for (int j = 0; j < CHUNK; ++j) {
      const float e = __expf(s[j] - m);  // padded: exp(-inf)=0
      denom += e;
      attn += hv[j] * e;
      meanv += hv[j] * mult[j];          // padded: mult=0
      const bool v2 = (j < rem);
      maxv.x = fmaxf(maxv.x, v2 ? hv[j].x : -INFINITY);
      maxv.y = fmaxf(maxv.y, v2 ? hv[j].y : -INFINITY);
      maxv.z = fmaxf(maxv.z, v2 ? hv[j].z : -INFINITY);
      maxv.w = fmaxf(maxv.w, v2 ? hv[j].w : -INFINITY);
      tmult += mult[j];
    }
  }

  // waves 1..3 publish; wave 0 merges and writes output
  if (q > 0) {
    if (lane == 0) { s_m[q - 1] = m; s_d[q - 1] = denom; s_t[q - 1] = tmult; }
    s_attn[q - 1][lane] = attn;
    s_mean[q - 1][lane] = meanv;
    s_max[q - 1][lane]  = maxv;
  }
  __syncthreads();

  if (q == 0) {
    float M = m, D = denom, T = tmult;
    fx4 A = attn, Me = meanv, Mx = maxv;
#pragma unroll
    for (int k = 0; k < 3; ++k) {
      const float mk = s_m[k];
      const float Mn = fmaxf(M, mk);
      const float sc0 = (M  == -INFINITY) ? 0.f : __expf(M  - Mn);
      const float sck = (mk == -INFINITY) ? 0.f : __expf(mk - Mn);
      D = D * sc0 + s_d[k] * sck;
      A = A * sc0 + s_attn[k][lane] * sck;
      M = Mn;
      Me += s_mean[k][lane];
      const fx4 mxk = s_max[k][lane];
      Mx.x = fmaxf(Mx.x, mxk.x);  Mx.y = fmaxf(Mx.y, mxk.y);
      Mx.z = fmaxf(Mx.z, mxk.z);  Mx.w = fmaxf(Mx.w, mxk.w);
      T += s_t[k];
    }

    const float inv_tm  = 1.f / fmaxf(T, 1e-8f);
    const float inv_den = (D > 0.f) ? 1.f / D : 0.f;
    const float p_norm  = pressure[g] * (1.f / 300.f);
    const fx4 wp4 = *reinterpret_cast<const fx4*>(W_pressure + 4 * lane);

    fx4 res = 0.5f * (Me * inv_tm + A * inv_den) + p_norm * wp4;

    float* outg = out + (size_t)g * (2 * HIDDEN);
    *reinterpret_cast<fx4*>(outg + 4 * lane) = res;
    *reinterpret_cast<fx4*>(outg + HIDDEN + 4 * lane) = Mx;
  }
}

extern "C" void kernel_launch(void* const* d_in, const int* in_sizes, int n_in,
                              void* d_out, int out_size, void* d_ws, size_t ws_size,
                              hipStream_t stream) {
  const float* h           = (const float*)d_in[0];
  const float* node_mult   = (const float*)d_in[1];
  const float* pressure    = (const float*)d_in[2];
  const float* attn_weight = (const float*)d_in[3];
  const float* attn_bias   = (const float*)d_in[4];
  const float* W_pressure  = (const float*)d_in[5];
  const int*   batch       = (const int*)d_in[6];

  const int N = in_sizes[1];
  const int G = in_sizes[2];

  float* out = (float*)d_out;

  pool_kernel<<<G, 256, 0, stream>>>(h, node_mult, pressure,
                                     attn_weight, attn_bias,
                                     W_pressure, batch, out, N, G);
}

// Round 9
// 112.357 us; speedup vs baseline: 1.2331x; 1.2331x over previous
//
#include <hip/hip_runtime.h>
#include <math.h>

#define HIDDEN 256
#define CHUNK 8

typedef float fx4 __attribute__((ext_vector_type(4)));

// Single fused kernel: block = 4 waves = 1 graph.
// Graph bounds found by a NON-DEPENDENT windowed scan around the analytic
// guess g*N/G (batch ids are Binomial -> sigma <= 354; window +-2048 = 5.8
// sigma; exponential widening fallback guarantees correctness). Wave 0 finds
// start, wave 1 finds end; ~4 independent int4 loads per lane, 6-shfl count
// reduce -- no 20-deep dependent chain (R8's failure), no second kernel (R6's
// launch+drain bubble).
__global__ __launch_bounds__(256) void pool_kernel(
    const float* __restrict__ h, const float* __restrict__ node_mult,
    const float* __restrict__ pressure, const float* __restrict__ attn_weight,
    const float* __restrict__ attn_bias, const float* __restrict__ W_pressure,
    const int* __restrict__ batch, float* __restrict__ out, int N, int G) {
  const int q    = threadIdx.x >> 6;   // wave 0..3
  const int lane = threadIdx.x & 63;
  const int g = blockIdx.x;

  __shared__ int s_bounds[2];
  __shared__ float s_m[3], s_d[3], s_t[3];
  __shared__ fx4 s_attn[3][64], s_mean[3][64], s_max[3][64];

  // waves 0,1: lower_bound(batch, g+q) via windowed parallel count
  if (q < 2) {
    const int v = g + q;
    const long long c = ((long long)v * N) / G;
    int half = 2048;
    int result = -1;
    while (result < 0) {
      int L = (int)c - half;
      if (L < 0) L = 0;
      L &= ~3;  // int4 alignment (N % 4 == 0)
      long long Rl = (long long)L + 2 * (long long)half;
      const int R = (Rl > N) ? N : (int)Rl;

      int cnt = 0;
      for (int base = L + 4 * lane; base < R; base += 256) {
        const int4 x = *reinterpret_cast<const int4*>(batch + base);
        cnt += (x.x < v) + (x.y < v) + (x.z < v) + (x.w < v);
      }
#pragma unroll
      for (int off = 32; off >= 1; off >>= 1) cnt += __shfl_xor(cnt, off, 64);

      const bool left_ok  = (L == 0) || (cnt > 0);
      const bool right_ok = (R == N) || (cnt < R - L);
      if (left_ok && right_ok) result = L + cnt;
      else half *= 16;  // rare fallback
    }
    if (lane == 0) s_bounds[q] = result;
  }
  __syncthreads();

  const int start = s_bounds[0];
  const int end   = s_bounds[1];
  const int total = end - start;
  const int nfull = total / CHUNK;          // full chunks
  const int rem   = total - nfull * CHUNK;  // 0..7
  const int nt    = nfull + (rem > 0);      // total chunks incl. masked

  const fx4 w4 = *reinterpret_cast<const fx4*>(attn_weight + 4 * lane);
  const float bias = attn_bias[0];

  fx4 attn  = (fx4)(0.f);
  fx4 meanv = (fx4)(0.f);
  fx4 maxv  = (fx4)(-INFINITY);
  float m = -INFINITY;
  float denom = 0.f;
  float tmult = 0.f;

  // this wave's chunk range [c_lo, c_hi) over all nt chunks
  const int c_lo = (q * nt) / 4;
  const int c_hi = ((q + 1) * nt) / 4;
  const int f_hi = (c_hi < nfull) ? c_hi : nfull;  // full-chunk part

  for (int c = c_lo; c < f_hi; ++c) {
    const int i = start + c * CHUNK;
    fx4 hv[CHUNK];
    float mult[CHUNK];
#pragma unroll
    for (int j = 0; j < CHUNK; ++j) {
      hv[j] = __builtin_nontemporal_load(
          reinterpret_cast<const fx4*>(h + (size_t)(i + j) * HIDDEN + 4 * lane));
      mult[j] = node_mult[i + j];
    }

    float p[CHUNK];
#pragma unroll
    for (int j = 0; j < CHUNK; ++j)
      p[j] = hv[j].x * w4.x + hv[j].y * w4.y + hv[j].z * w4.z + hv[j].w * w4.w;

#pragma unroll
    for (int off = 32; off >= 1; off >>= 1) {
#pragma unroll
      for (int j = 0; j < CHUNK; ++j) p[j] += __shfl_xor(p[j], off, 64);
    }

    float s[CHUNK];
#pragma unroll
    for (int j = 0; j < CHUNK; ++j)
      s[j] = p[j] + bias + __logf(fmaxf(mult[j], 1.f));

    float cmax = s[0];
#pragma unroll
    for (int j = 1; j < CHUNK; ++j) cmax = fmaxf(cmax, s[j]);

    if (cmax > m) {
      const float scale = __expf(m - cmax);  // m=-inf -> 0
      denom *= scale;
      attn *= scale;
      m = cmax;
    }

#pragma unroll
    for (int j = 0; j < CHUNK; ++j) {
      const float e = __expf(s[j] - m);
      denom += e;
      attn += hv[j] * e;
      meanv += hv[j] * mult[j];
      maxv.x = fmaxf(maxv.x, hv[j].x);  maxv.y = fmaxf(maxv.y, hv[j].y);
      maxv.z = fmaxf(maxv.z, hv[j].z);  maxv.w = fmaxf(maxv.w, hv[j].w);
      tmult += mult[j];
    }
  }

  // masked remainder chunk (1..7 nodes), owned by the wave whose range has it
  if (rem > 0 && c_lo <= nfull && nfull < c_hi) {
    const int base = start + nfull * CHUNK;
    fx4 hv[CHUNK];
    float mult[CHUNK];
#pragma unroll
    for (int j = 0; j < CHUNK; ++j) {
      const int idx = base + ((j < rem) ? j : rem - 1);  // clamped, in-bounds
      hv[j] = __builtin_nontemporal_load(
          reinterpret_cast<const fx4*>(h + (size_t)idx * HIDDEN + 4 * lane));
      mult[j] = (j < rem) ? node_mult[base + j] : 0.f;
    }

    float p[CHUNK];
#pragma unroll
    for (int j = 0; j < CHUNK; ++j)
      p[j] = hv[j].x * w4.x + hv[j].y * w4.y + hv[j].z * w4.z + hv[j].w * w4.w;

#pragma unroll
    for (int off = 32; off >= 1; off >>= 1) {
#pragma unroll
      for (int j = 0; j < CHUNK; ++j) p[j] += __shfl_xor(p[j], off, 64);
    }

    float s[CHUNK];
#pragma unroll
    for (int j = 0; j < CHUNK; ++j)
      s[j] = (j < rem) ? (p[j] + bias + __logf(fmaxf(mult[j], 1.f))) : -INFINITY;

    float cmax = s[0];
#pragma unroll
    for (int j = 1; j < CHUNK; ++j) cmax = fmaxf(cmax, s[j]);

    if (cmax > m) {
      const float scale = __expf(m - cmax);
      denom *= scale;
      attn *= scale;
      m = cmax;
    }

#pragma unroll
    for (int j = 0; j < CHUNK; ++j) {
      const float e = __expf(s[j] - m);  // padded: exp(-inf)=0
      denom += e;
      attn += hv[j] * e;
      meanv += hv[j] * mult[j];          // padded: mult=0
      const bool v2 = (j < rem);
      maxv.x = fmaxf(maxv.x, v2 ? hv[j].x : -INFINITY);
      maxv.y = fmaxf(maxv.y, v2 ? hv[j].y : -INFINITY);
      maxv.z = fmaxf(maxv.z, v2 ? hv[j].z : -INFINITY);
      maxv.w = fmaxf(maxv.w, v2 ? hv[j].w : -INFINITY);
      tmult += mult[j];
    }
  }

  // waves 1..3 publish; wave 0 merges and writes output
  if (q > 0) {
    if (lane == 0) { s_m[q - 1] = m; s_d[q - 1] = denom; s_t[q - 1] = tmult; }
    s_attn[q - 1][lane] = attn;
    s_mean[q - 1][lane] = meanv;
    s_max[q - 1][lane]  = maxv;
  }
  __syncthreads();

  if (q == 0) {
    float M = m, D = denom, T = tmult;
    fx4 A = attn, Me = meanv, Mx = maxv;
#pragma unroll
    for (int k = 0; k < 3; ++k) {
      const float mk = s_m[k];
      const float Mn = fmaxf(M, mk);
      const float sc0 = (M  == -INFINITY) ? 0.f : __expf(M  - Mn);
      const float sck = (mk == -INFINITY) ? 0.f : __expf(mk - Mn);
      D = D * sc0 + s_d[k] * sck;
      A = A * sc0 + s_attn[k][lane] * sck;
      M = Mn;
      Me += s_mean[k][lane];
      const fx4 mxk = s_max[k][lane];
      Mx.x = fmaxf(Mx.x, mxk.x);  Mx.y = fmaxf(Mx.y, mxk.y);
      Mx.z = fmaxf(Mx.z, mxk.z);  Mx.w = fmaxf(Mx.w, mxk.w);
      T += s_t[k];
    }

    const float inv_tm  = 1.f / fmaxf(T, 1e-8f);
    const float inv_den = (D > 0.f) ? 1.f / D : 0.f;
    const float p_norm  = pressure[g] * (1.f / 300.f);
    const fx4 wp4 = *reinterpret_cast<const fx4*>(W_pressure + 4 * lane);

    fx4 res = 0.5f * (Me * inv_tm + A * inv_den) + p_norm * wp4;

    float* outg = out + (size_t)g * (2 * HIDDEN);
    *reinterpret_cast<fx4*>(outg + 4 * lane) = res;
    *reinterpret_cast<fx4*>(outg + HIDDEN + 4 * lane) = Mx;
  }
}

extern "C" void kernel_launch(void* const* d_in, const int* in_sizes, int n_in,
                              void* d_out, int out_size, void* d_ws, size_t ws_size,
                              hipStream_t stream) {
  const float* h           = (const float*)d_in[0];
  const float* node_mult   = (const float*)d_in[1];
  const float* pressure    = (const float*)d_in[2];
  const float* attn_weight = (const float*)d_in[3];
  const float* attn_bias   = (const float*)d_in[4];
  const float* W_pressure  = (const float*)d_in[5];
  const int*   batch       = (const int*)d_in[6];

  const int N = in_sizes[1];
  const int G = in_sizes[2];

  float* out = (float*)d_out;

  pool_kernel<<<G, 256, 0, stream>>>(h, node_mult, pressure,
                                     attn_weight, attn_bias,
                                     W_pressure, batch, out, N, G);
}

// Round 10
// 97.663 us; speedup vs baseline: 1.4186x; 1.1505x over previous
//
#include <hip/hip_runtime.h>
#include <math.h>

#define HIDDEN 256
#define CHUNK 8

typedef float fx4 __attribute__((ext_vector_type(4)));

// Kernel 1: build segment boundary array starts[0..G] from sorted batch ids.
__global__ __launch_bounds__(256) void seg_starts_kernel(
    const int* __restrict__ batch, int* __restrict__ starts, int N, int G) {
  int i = blockIdx.x * blockDim.x + threadIdx.x;
  if (i >= N) return;
  int b = batch[i];
  int prev = (i == 0) ? -1 : batch[i - 1];
  for (int g = prev + 1; g <= b; ++g) starts[g] = i;
  if (i == N - 1) {
    for (int g = b + 1; g <= G; ++g) starts[g] = N;
  }
}

// Kernel 2: block = 4 waves = 1 graph; each wave takes a quarter of the
// graph's chunks (contiguous), remainder is a masked vector chunk owned by
// the wave whose range contains it; 4 online-softmax states merged via LDS.
// (R6 structure — best measured: 98.3 us. R7 8-wave split, R8 binary search,
// R9 windowed scan all regressed; per-block prologue costs multiply by 8192.)
__global__ __launch_bounds__(256) void pool_kernel(
    const float* __restrict__ h, const float* __restrict__ node_mult,
    const float* __restrict__ pressure, const float* __restrict__ attn_weight,
    const float* __restrict__ attn_bias, const float* __restrict__ W_pressure,
    const int* __restrict__ starts, float* __restrict__ out, int G) {
  const int q    = threadIdx.x >> 6;   // wave 0..3 = quarter index
  const int lane = threadIdx.x & 63;
  const int g = blockIdx.x;

  __shared__ float s_m[3], s_d[3], s_t[3];
  __shared__ fx4 s_attn[3][64], s_mean[3][64], s_max[3][64];

  const int start = starts[g];
  const int end   = starts[g + 1];
  const int total = end - start;
  const int nfull = total / CHUNK;          // full chunks
  const int rem   = total - nfull * CHUNK;  // 0..7
  const int nt    = nfull + (rem > 0);      // total chunks incl. masked

  const fx4 w4 = *reinterpret_cast<const fx4*>(attn_weight + 4 * lane);
  const float bias = attn_bias[0];

  fx4 attn  = (fx4)(0.f);
  fx4 meanv = (fx4)(0.f);
  fx4 maxv  = (fx4)(-INFINITY);
  float m = -INFINITY;
  float denom = 0.f;
  float tmult = 0.f;

  // this wave's chunk range [c_lo, c_hi) over all nt chunks
  const int c_lo = (q * nt) / 4;
  const int c_hi = ((q + 1) * nt) / 4;
  const int f_hi = (c_hi < nfull) ? c_hi : nfull;  // full-chunk part

  for (int c = c_lo; c < f_hi; ++c) {
    const int i = start + c * CHUNK;
    fx4 hv[CHUNK];
    float mult[CHUNK];
#pragma unroll
    for (int j = 0; j < CHUNK; ++j) {
      hv[j] = __builtin_nontemporal_load(
          reinterpret_cast<const fx4*>(h + (size_t)(i + j) * HIDDEN + 4 * lane));
      mult[j] = node_mult[i + j];
    }

    float p[CHUNK];
#pragma unroll
    for (int j = 0; j < CHUNK; ++j)
      p[j] = hv[j].x * w4.x + hv[j].y * w4.y + hv[j].z * w4.z + hv[j].w * w4.w;

#pragma unroll
    for (int off = 32; off >= 1; off >>= 1) {
#pragma unroll
      for (int j = 0; j < CHUNK; ++j) p[j] += __shfl_xor(p[j], off, 64);
    }

    float s[CHUNK];
#pragma unroll
    for (int j = 0; j < CHUNK; ++j)
      s[j] = p[j] + bias + __logf(fmaxf(mult[j], 1.f));

    float cmax = s[0];
#pragma unroll
    for (int j = 1; j < CHUNK; ++j) cmax = fmaxf(cmax, s[j]);

    if (cmax > m) {
      const float scale = __expf(m - cmax);  // m=-inf -> 0
      denom *= scale;
      attn *= scale;
      m = cmax;
    }

#pragma unroll
    for (int j = 0; j < CHUNK; ++j) {
      const float e = __expf(s[j] - m);
      denom += e;
      attn += hv[j] * e;
      meanv += hv[j] * mult[j];
      maxv.x = fmaxf(maxv.x, hv[j].x);  maxv.y = fmaxf(maxv.y, hv[j].y);
      maxv.z = fmaxf(maxv.z, hv[j].z);  maxv.w = fmaxf(maxv.w, hv[j].w);
      tmult += mult[j];
    }
  }

  // masked remainder chunk (1..7 nodes), owned by the wave whose range has it
  if (rem > 0 && c_lo <= nfull && nfull < c_hi) {
    const int base = start + nfull * CHUNK;
    fx4 hv[CHUNK];
    float mult[CHUNK];
#pragma unroll
    for (int j = 0; j < CHUNK; ++j) {
      const int idx = base + ((j < rem) ? j : rem - 1);  // clamped, in-bounds
      hv[j] = __builtin_nontemporal_load(
          reinterpret_cast<const fx4*>(h + (size_t)idx * HIDDEN + 4 * lane));
      mult[j] = (j < rem) ? node_mult[base + j] : 0.f;
    }

    float p[CHUNK];
#pragma unroll
    for (int j = 0; j < CHUNK; ++j)
      p[j] = hv[j].x * w4.x + hv[j].y * w4.y + hv[j].z * w4.z + hv[j].w * w4.w;

#pragma unroll
    for (int off = 32; off >= 1; off >>= 1) {
#pragma unroll
      for (int j = 0; j < CHUNK; ++j) p[j] += __shfl_xor(p[j], off, 64);
    }

    float s[CHUNK];
#pragma unroll
    for (int j = 0; j < CHUNK; ++j)
      s[j] = (j < rem) ? (p[j] + bias + __logf(fmaxf(mult[j], 1.f))) : -INFINITY;

    float cmax = s[0];
#pragma unroll
    for (int j = 1; j < CHUNK; ++j) cmax = fmaxf(cmax, s[j]);

    if (cmax > m) {
      const float scale = __expf(m - cmax);
      denom *= scale;
      attn *= scale;
      m = cmax;
    }

#pragma unroll
    for (int j = 0; j < CHUNK; ++j) {
      const float e = __expf(s[j] - m);  // padded: exp(-inf)=0
      denom += e;
      attn += hv[j] * e;
      meanv += hv[j] * mult[j];          // padded: mult=0
      const bool v2 = (j < rem);
      maxv.x = fmaxf(maxv.x, v2 ? hv[j].x : -INFINITY);
      maxv.y = fmaxf(maxv.y, v2 ? hv[j].y : -INFINITY);
      maxv.z = fmaxf(maxv.z, v2 ? hv[j].z : -INFINITY);
      maxv.w = fmaxf(maxv.w, v2 ? hv[j].w : -INFINITY);
      tmult += mult[j];
    }
  }

  // waves 1..3 publish; wave 0 merges and writes output
  if (q > 0) {
    if (lane == 0) { s_m[q - 1] = m; s_d[q - 1] = denom; s_t[q - 1] = tmult; }
    s_attn[q - 1][lane] = attn;
    s_mean[q - 1][lane] = meanv;
    s_max[q - 1][lane]  = maxv;
  }
  __syncthreads();

  if (q == 0) {
    float M = m, D = denom, T = tmult;
    fx4 A = attn, Me = meanv, Mx = maxv;
#pragma unroll
    for (int k = 0; k < 3; ++k) {
      const float mk = s_m[k];
      const float Mn = fmaxf(M, mk);
      const float sc0 = (M  == -INFINITY) ? 0.f : __expf(M  - Mn);
      const float sck = (mk == -INFINITY) ? 0.f : __expf(mk - Mn);
      D = D * sc0 + s_d[k] * sck;
      A = A * sc0 + s_attn[k][lane] * sck;
      M = Mn;
      Me += s_mean[k][lane];
      const fx4 mxk = s_max[k][lane];
      Mx.x = fmaxf(Mx.x, mxk.x);  Mx.y = fmaxf(Mx.y, mxk.y);
      Mx.z = fmaxf(Mx.z, mxk.z);  Mx.w = fmaxf(Mx.w, mxk.w);
      T += s_t[k];
    }

    const float inv_tm  = 1.f / fmaxf(T, 1e-8f);
    const float inv_den = (D > 0.f) ? 1.f / D : 0.f;
    const float p_norm  = pressure[g] * (1.f / 300.f);
    const fx4 wp4 = *reinterpret_cast<const fx4*>(W_pressure + 4 * lane);

    fx4 res = 0.5f * (Me * inv_tm + A * inv_den) + p_norm * wp4;

    float* outg = out + (size_t)g * (2 * HIDDEN);
    *reinterpret_cast<fx4*>(outg + 4 * lane) = res;
    *reinterpret_cast<fx4*>(outg + HIDDEN + 4 * lane) = Mx;
  }
}

extern "C" void kernel_launch(void* const* d_in, const int* in_sizes, int n_in,
                              void* d_out, int out_size, void* d_ws, size_t ws_size,
                              hipStream_t stream) {
  const float* h           = (const float*)d_in[0];
  const float* node_mult   = (const float*)d_in[1];
  const float* pressure    = (const float*)d_in[2];
  const float* attn_weight = (const float*)d_in[3];
  const float* attn_bias   = (const float*)d_in[4];
  const float* W_pressure  = (const float*)d_in[5];
  const int*   batch       = (const int*)d_in[6];

  const int N = in_sizes[1];
  const int G = in_sizes[2];

  int* starts = (int*)d_ws;
  float* out = (float*)d_out;

  seg_starts_kernel<<<(N + 255) / 256, 256, 0, stream>>>(batch, starts, N, G);
  pool_kernel<<<G, 256, 0, stream>>>(h, node_mult, pressure,
                                     attn_weight, attn_bias,
                                     W_pressure, starts, out, G);
}